// Round 9
// baseline (13716.193 us; speedup 1.0000x reference)
//
#include <hip/hip_runtime.h>
#include <hip/hip_fp16.h>

typedef __attribute__((ext_vector_type(4))) float f32x4;
typedef _Float16 f16;
typedef __attribute__((ext_vector_type(4))) _Float16 f16x4;
typedef __attribute__((ext_vector_type(8))) _Float16 f16x8;

#define DEV static __device__ __forceinline__

constexpr int B_ = 128, T_ = 2048, H_ = 256, TRG_ = 24;
constexpr int NBLK = 8;   // encoder blocks, 16 batches each

// ---------------- workspace layout (~150 MiB) ----------------
constexpr size_t XF_OFF   = 0;                                   // x A-fragments [t][blk][bb][32] f16
constexpr size_t XF_BYTES = (size_t)T_ * NBLK * 16 * 32 * 2;     // 16 MiB
constexpr size_t OUTS_OFF = XF_OFF + XF_BYTES;
constexpr size_t OUTS_BYTES = (size_t)B_ * T_ * H_ * 2;          // 128 MiB f16
constexpr size_t EPROJ_OFF = OUTS_OFF + OUTS_BYTES;
constexpr size_t EPROJ_BYTES = (size_t)B_ * T_ * 4;              // 1 MiB
constexpr size_t HH_OFF = EPROJ_OFF + EPROJ_BYTES;               // ping-pong decoder h (buf0 = enc final)
constexpr size_t HH_BYTES = 2ull * B_ * H_ * 4;
constexpr size_t CC_OFF = HH_OFF + HH_BYTES;
constexpr size_t CC_BYTES = (size_t)B_ * H_ * 4;
constexpr size_t WXD_OFF = CC_OFF + CC_BYTES;                    // Wih_d[:,1:] @ Wfc (1024x256) f32
constexpr size_t WXD_BYTES = 1024ull * 256 * 4;
constexpr size_t VV_OFF = WXD_OFF + WXD_BYTES;
constexpr size_t VV_BYTES = 8192;
constexpr size_t WFR_OFF = VV_OFF + VV_BYTES;                    // reg-resident frag image ks0-3
constexpr size_t WFR_BYTES = 256ull * 64 * 16;                   // 256 KiB
constexpr size_t WLL_OFF = WFR_OFF + WFR_BYTES;                  // LDS frag image ks4-5
constexpr size_t WLL_BYTES = 128ull * 64 * 16;                   // 128 KiB
constexpr size_t WST_OFF = WLL_OFF + WLL_BYTES;                  // streamed frags ks6,7,x (x2 copies)
constexpr size_t WST_BYTES = 2ull * 192 * 64 * 16;               // 384 KiB
constexpr size_t ZERO_OFF = WST_OFF + WST_BYTES;
constexpr size_t CTX_CNT = 24ull * 128 * 257;   // ctxacc
constexpr size_t SAC_CNT = 25ull * 128;         // s_acc
constexpr size_t PRD_CNT = 24ull * 128;         // pred_acc
constexpr size_t INP_CNT = 25ull * 128;         // inp_buf
constexpr size_t ZERO_CNT = CTX_CNT + SAC_CNT + PRD_CNT + INP_CNT;
constexpr size_t WS_NEED = ZERO_OFF + ZERO_CNT * 4 + 1024;

// ---------------- helpers ----------------
DEV float sigf(float x)  { return 1.0f / (1.0f + __expf(-x)); }
DEV float tanh_(float x) { return 1.0f - 2.0f / (__expf(2.0f * x) + 1.0f); }

__global__ void k_wsfail(float* __restrict__ dout, float mb) { dout[0] = 1e6f + mb; }

__global__ void k_zero(float* __restrict__ p, size_t n) {
  size_t i = (size_t)blockIdx.x * blockDim.x + threadIdx.x;
  size_t s = (size_t)gridDim.x * blockDim.x;
  for (; i < n; i += s) p[i] = 0.f;
}

// ---------------- small precomputed vectors ----------------
__global__ void k_prep(const float* __restrict__ Wfc, const float* __restrict__ Wa,
                       const float* __restrict__ Wf2, const float* __restrict__ bf2_,
                       const float* __restrict__ bfc, const float* __restrict__ bihd,
                       const float* __restrict__ bhhd, const float* __restrict__ Wihd,
                       float* __restrict__ vv) {
  const int blk = blockIdx.x, tid = threadIdx.x;
  if (blk == 0) {
    float a = 0; for (int h = 0; h < 256; ++h) a += Wfc[h * 256 + tid] * Wa[256 + h];
    vv[tid] = a;
  } else if (blk == 1) {
    float a = 0; for (int h = 0; h < 256; ++h) a += Wfc[h * 256 + tid] * Wf2[h];
    vv[256 + tid] = a;
  } else if (blk == 2) {
    if (tid == 0) { float a = 0; for (int h = 0; h < 256; ++h) a += bfc[h] * Wa[256 + h]; vv[512] = a; }
    if (tid == 1) { float a = bf2_[0]; for (int h = 0; h < 256; ++h) a += bfc[h] * Wf2[h]; vv[513] = a; }
  } else if (blk < 7) {
    int j = (blk - 3) * 256 + tid;
    float a = bihd[j] + bhhd[j];
    for (int h = 0; h < 256; ++h) a += Wihd[j * 257 + 1 + h] * bfc[h];
    vv[576 + j] = a;
  }
}

// Wxd[j][k] = sum_h Wih_d[j][1+h] * Wfc[h][k]  (64 blocks x 16 rows)
__global__ void k_wxd(const float* __restrict__ Wihd, const float* __restrict__ Wfc,
                      float* __restrict__ wxd) {
  __shared__ float sR[16][256];
  const int tid = threadIdx.x;
  for (int i = tid; i < 16 * 256; i += 256) {
    int r = i >> 8, h = i & 255;
    sR[r][h] = Wihd[(blockIdx.x * 16 + r) * 257 + 1 + h];
  }
  __syncthreads();
  const int k = tid;
  float a[16];
#pragma unroll
  for (int r = 0; r < 16; ++r) a[r] = 0.f;
  for (int h = 0; h < 256; ++h) {
    float wv = Wfc[h * 256 + k];
#pragma unroll
    for (int r = 0; r < 16; ++r) a[r] += sR[r][h] * wv;
  }
#pragma unroll
  for (int r = 0; r < 16; ++r) wxd[(blockIdx.x * 16 + r) * 256 + k] = a[r];
}

// ---------------- encoder weight fragment images (f16, MFMA B-fragment order) ----------------
// tile (q=gate, om=jcol16): row = 256q + 16om + c16.
// wfr: fid=(om*4+q)*4+ks   (ks0-3)   -> registers
// wll: fid=(om*4+q)*2+ks2  (ks4-5)   -> LDS
// wst: fid=(om*4+q)*3+ks3  (ks3:0,1=Whh ks6,7 ; 2=x/bias) x2 copies -> streamed
__global__ void k_wprep3(const float* __restrict__ Whh, const float* __restrict__ Wih,
                         const float* __restrict__ bih, const float* __restrict__ bhh,
                         f16* __restrict__ wfr, f16* __restrict__ wll, f16* __restrict__ wst) {
  int i = blockIdx.x * 256 + threadIdx.x;
  int l = i & 63, fid = i >> 6;
  int g = l >> 4, c16 = l & 15;
  if (fid < 256) {
    int ks = fid & 3, q = (fid >> 2) & 3, om = fid >> 4;
    int row = 256 * q + 16 * om + c16;
    f16x8 v;
#pragma unroll
    for (int jj = 0; jj < 8; ++jj) v[jj] = (f16)Whh[row * 256 + ks * 32 + 8 * g + jj];
    ((f16x8*)wfr)[fid * 64 + l] = v;
  } else if (fid < 384) {
    int f2 = fid - 256;
    int ks2 = f2 & 1, q = (f2 >> 1) & 3, om = f2 >> 3;
    int row = 256 * q + 16 * om + c16;
    f16x8 v;
#pragma unroll
    for (int jj = 0; jj < 8; ++jj) v[jj] = (f16)Whh[row * 256 + (4 + ks2) * 32 + 8 * g + jj];
    ((f16x8*)wll)[f2 * 64 + l] = v;
  } else if (fid < 576) {
    int f3 = fid - 384;
    int ks3 = f3 % 3, qw = f3 / 3;
    int q = qw & 3, om = qw >> 2;
    int row = 256 * q + 16 * om + c16;
    f16x8 v;
    if (ks3 < 2) {
#pragma unroll
      for (int jj = 0; jj < 8; ++jj) v[jj] = (f16)Whh[row * 256 + (6 + ks3) * 32 + 8 * g + jj];
    } else {
#pragma unroll
      for (int jj = 0; jj < 8; ++jj) {
        int k = 8 * g + jj;
        float val = (k < 16) ? Wih[row * 16 + k] : (k == 16 ? (bih[row] + bhh[row]) : 0.f);
        v[jj] = (f16)val;
      }
    }
    ((f16x8*)wst)[f3 * 64 + l] = v;
    ((f16x8*)wst)[12288 + f3 * 64 + l] = v;    // copy 1
  }
}

// ---------------- x A-fragment prepass (coalesced) ----------------
__global__ __launch_bounds__(128) void k_xf(const float* __restrict__ src1,
    const float* __restrict__ src2, const float* __restrict__ Wc, const float* __restrict__ bc,
    f16* __restrict__ xf) {
  const int b = blockIdx.x >> 4, tc = blockIdx.x & 15;
  const int t = tc * 128 + threadIdx.x;
  f16x8 v0, v1, v2, v3;
#pragma unroll
  for (int f = 0; f < 8; ++f)  v0[f] = (f16)src1[((size_t)b * T_ + t) * 15 + f];
#pragma unroll
  for (int f = 0; f < 7; ++f)  v1[f] = (f16)src1[((size_t)b * T_ + t) * 15 + 8 + f];
  float s = bc[0];
#pragma unroll
  for (int u = 0; u < 8; ++u) s += src2[((size_t)b * T_ + t) * 8 + u] * Wc[u];
  v1[7] = (f16)s;
  v2 = (f16x8){(f16)1.f, (f16)0.f, (f16)0.f, (f16)0.f, (f16)0.f, (f16)0.f, (f16)0.f, (f16)0.f};
  v3 = (f16x8){(f16)0.f, (f16)0.f, (f16)0.f, (f16)0.f, (f16)0.f, (f16)0.f, (f16)0.f, (f16)0.f};
  f16* o = xf + (((size_t)t * 8 + (b >> 4)) * 16 + (b & 15)) * 32;
  *(f16x8*)(o) = v0; *(f16x8*)(o + 8) = v1; *(f16x8*)(o + 16) = v2; *(f16x8*)(o + 24) = v3;
}

// ---------------- encoder: 8 blocks x 1024 thr (16 waves); ks0-3 regs, ks4-5 LDS, rest stream --
__global__ __attribute__((amdgpu_flat_work_group_size(1024, 1024)))
           __attribute__((amdgpu_waves_per_eu(4)))
void k_enc3(const f16* __restrict__ wfr, const f16* __restrict__ wll,
            const f16* __restrict__ wst, const f16* __restrict__ xf,
            f16* __restrict__ outs, float* __restrict__ hh0, float* __restrict__ cc0) {
  const int blk = blockIdx.x, tid = threadIdx.x;
  const int om = tid >> 6, l = tid & 63, g = l >> 4, c16 = l & 15;
  __shared__ f16x8 Wl[8192];                      // ks4,5 frags = 128 KiB (same layout as wll)
  __shared__ __align__(16) f16 hbuf[2][16 * 260]; // ping-pong h[b][jh], stride 260

  for (int i2 = tid; i2 < 8192; i2 += 1024) Wl[i2] = ((const f16x8*)wll)[i2];
  // register-resident ks0-3 (16 frags = 64 VGPRs)
  f16x8 wf[4][4];
#pragma unroll
  for (int q = 0; q < 4; ++q)
#pragma unroll
    for (int ks = 0; ks < 4; ++ks)
      wf[q][ks] = ((const f16x8*)wfr)[(size_t)(((om * 4 + q) * 4) + ks) * 64 + l];
  for (int i2 = tid; i2 < 16 * 260; i2 += 1024) hbuf[0][i2] = (f16)0.f;
  __syncthreads();
#pragma unroll
  for (int q = 0; q < 4; ++q)
#pragma unroll
    for (int ks = 0; ks < 4; ++ks) asm volatile("" : "+v"(wf[q][ks]));

  float cst[4] = {0.f, 0.f, 0.f, 0.f};
  const f16x8* wstv = (const f16x8*)wst;
  const int jh = 16 * om + c16;
  const int ou = l;                              // outs-writer: wave om = batch om, lane = H/4 chunk

#define LDA(ks) ({ const f16* hp = hb + c16 * 260 + (ks) * 32 + 8 * g; \
                   f16x4 a0 = *(const f16x4*)hp; f16x4 a1 = *(const f16x4*)(hp + 4); \
                   f16x8 a; a[0]=a0[0];a[1]=a0[1];a[2]=a0[2];a[3]=a0[3]; \
                   a[4]=a1[0];a[5]=a1[1];a[6]=a1[2];a[7]=a1[3]; a; })
#define STG(S) \
  { _Pragma("unroll") for (int q = 0; q < 4; ++q) \
      st[q] = sw[(size_t)((om * 4 + q) * 3 + (S)) * 64 + l]; }
#define MFW(A, KS) \
  { _Pragma("unroll") for (int q = 0; q < 4; ++q) \
      acc[q] = __builtin_amdgcn_mfma_f32_16x16x32_f16((A), wf[q][KS], acc[q], 0, 0, 0); }
#define MFS(A) \
  { _Pragma("unroll") for (int q = 0; q < 4; ++q) \
      acc[q] = __builtin_amdgcn_mfma_f32_16x16x32_f16((A), st[q], acc[q], 0, 0, 0); }
#define MFL(A, KS2) \
  { _Pragma("unroll") for (int q = 0; q < 4; ++q) \
      acc[q] = __builtin_amdgcn_mfma_f32_16x16x32_f16((A), Wl[((om * 4 + q) * 2 + (KS2)) * 64 + l], acc[q], 0, 0, 0); }

  for (int t = 0; t < T_; ++t) {
    const int cp = t & 1;
    const f16* hb = hbuf[cp];
    const f16x8* sw = wstv + (size_t)cp * 12288;

    f16x8 st[4];
    STG(2);                                      // x-B frags (consumed after ks0-3)
    const f16x8 xa = *(const f16x8*)(xf + (((size_t)t * 8 + blk) * 16 + c16) * 32 + 8 * g);

    // deferred coalesced outs write of h(t-1) (8B/thread)
    if (t > 0) {
      const f16x4 hv = *(const f16x4*)(hb + om * 260 + ou * 4);
      *(f16x4*)(outs + ((size_t)(blk * 16 + om) * T_ + (t - 1)) * H_ + ou * 4) = hv;
    }

    f32x4 acc[4];
#pragma unroll
    for (int q = 0; q < 4; ++q) acc[q] = (f32x4){0.f, 0.f, 0.f, 0.f};

    { const f16x8 a = LDA(0); MFW(a, 0); }
    { const f16x8 a = LDA(1); MFW(a, 1); }
    { const f16x8 a = LDA(2); MFW(a, 2); }
    { const f16x8 a = LDA(3); MFW(a, 3); }
    MFS(xa);                                     // x part (+bias via k=16)
    STG(0);                                      // ks6
    { const f16x8 a = LDA(4); MFL(a, 0); }
    { const f16x8 a = LDA(6); MFS(a); }
    STG(1);                                      // ks7
    { const f16x8 a = LDA(5); MFL(a, 1); }
    { const f16x8 a = LDA(7); MFS(a); }

    // epilogue: 4 cells/thread (i,f,g,o = acc[0..3]), write h into ping-pong buffer
    f16* hw = hbuf[cp ^ 1];
#pragma unroll
    for (int r = 0; r < 4; ++r) {
      const float iv = acc[0][r], fv = acc[1][r], gv = acc[2][r], ov = acc[3][r];
      const float cn = sigf(fv) * cst[r] + sigf(iv) * tanh_(gv);
      cst[r] = cn;
      const float hn = sigf(ov) * tanh_(cn);
      const int bl = 4 * g + r;
      hw[bl * 260 + jh] = (f16)hn;
      if (t == T_ - 1) {
        hh0[(blk * 16 + bl) * H_ + jh] = hn;
        cc0[(blk * 16 + bl) * H_ + jh] = cn;
      }
    }
    __syncthreads();
  }
  // final outs row: h(T-1) lives in hbuf[0] (T even)
  {
    const f16x4 hv = *(const f16x4*)(hbuf[0] + om * 260 + ou * 4);
    *(f16x4*)(outs + ((size_t)(blk * 16 + om) * T_ + (T_ - 1)) * H_ + ou * 4) = hv;
  }
#undef LDA
#undef STG
#undef MFW
#undef MFS
#undef MFL
}

// ---------------- eproj = outs.v + c0 ----------------
__global__ __launch_bounds__(256) void k_eproj(const f16* __restrict__ outs,
    const float* __restrict__ vv, float* __restrict__ eproj) {
  const int l = threadIdx.x & 63, wv = threadIdx.x >> 6;
  const float v0 = vv[4 * l], v1 = vv[4 * l + 1], v2 = vv[4 * l + 2], v3 = vv[4 * l + 3];
  const float c0 = vv[512];
  const int base = blockIdx.x * 256;
  for (int it = 0; it < 64; ++it) {
    const int row = base + it * 4 + wv;
    const f16x4 o = *(const f16x4*)(outs + (size_t)row * H_ + l * 4);
    float s = (float)o[0] * v0 + (float)o[1] * v1 + (float)o[2] * v2 + (float)o[3] * v3;
#pragma unroll
    for (int off = 32; off > 0; off >>= 1) s += __shfl_down(s, off);
    if (l == 0) eproj[row] = s + c0;
  }
}

// ---------------- decoder init: token + s0 ----------------
__global__ void k_decinit(const f16* __restrict__ outs, const float* __restrict__ hh,
                          const float* __restrict__ Wa, const float* __restrict__ vv,
                          float* __restrict__ inp_buf, float* __restrict__ s_acc) {
  int b = threadIdx.x;
  if (b >= B_) return;
  float tok = vv[513];
  const f16* op = outs + ((size_t)b * T_ + (T_ - 1)) * H_;
  for (int k = 0; k < H_; ++k) tok += (float)op[k] * vv[256 + k];
  float s0 = 0;
  for (int j = 0; j < H_; ++j) s0 += hh[b * H_ + j] * Wa[j];
  inp_buf[b] = tok;
  s_acc[b] = s0;
}

// ---------------- attention: ctx' = softmax(tanh(s+eproj)) @ outs ----------------
__global__ void k_attn(int d, const float* __restrict__ eproj, const f16* __restrict__ outs,
                       const float* __restrict__ s_acc, float* __restrict__ ctxacc,
                       const float* __restrict__ pred_acc, float* __restrict__ inp_buf,
                       float* __restrict__ dout, const float* __restrict__ bo) {
  const int b = blockIdx.x >> 4, ch = blockIdx.x & 15;
  const int k = threadIdx.x;
  if (d > 0 && ch == 0 && k == 0) {
    float pv = pred_acc[(d - 1) * B_ + b] + bo[0];
    inp_buf[d * B_ + b] = pv;
    dout[b * TRG_ + (d - 1)] = pv;
  }
  __shared__ float swt[128];
  const float s = s_acc[d * B_ + b];
  if (k < 128) {
    float e = eproj[b * T_ + ch * 128 + k];
    swt[k] = __expf(tanh_(s + e));
  }
  __syncthreads();
  float acc = 0.f;
  const f16* op = outs + ((size_t)b * T_ + ch * 128) * H_ + k;
#pragma unroll 8
  for (int tt = 0; tt < 128; ++tt) acc += swt[tt] * (float)op[tt * H_];
  atomicAdd(&ctxacc[((size_t)d * B_ + b) * 257 + k], acc);
  if (k == 0) {
    float sw = 0;
    for (int tt = 0; tt < 128; ++tt) sw += swt[tt];
    atomicAdd(&ctxacc[((size_t)d * B_ + b) * 257 + 256], sw);
  }
}

// ---------------- decoder LSTM cell (128 blocks: 64 jb x 2 batch-halves) ----------------
__global__ __launch_bounds__(512) void k_cell(int d, const float* __restrict__ wxd,
    const float* __restrict__ Whhd, const float* __restrict__ Wihd, const float* __restrict__ vv,
    const float* __restrict__ ctxacc, const float* __restrict__ inp_buf,
    float* __restrict__ hh, float* __restrict__ cc,
    float* __restrict__ s_acc, float* __restrict__ pred_acc,
    const float* __restrict__ Wa, const float* __restrict__ Wo) {
  const int jb = blockIdx.x & 63, half = blockIdx.x >> 6;
  const int tid = threadIdx.x;
  const int rr = tid & 15, bb = tid >> 4;
  __shared__ float sW[16][516];
  __shared__ float sX[32][516];
  __shared__ float sG[32][17];
  __shared__ float sden[32], sinp[32];
  __shared__ float scol0[16], sbias[16];
  const float* bdp = vv + 576;
  for (int idx = tid; idx < 16 * 512; idx += 512) {
    int r2 = idx >> 9, k2 = idx & 511;
    int row = 256 * (r2 >> 2) + 4 * jb + (r2 & 3);
    sW[r2][k2] = (k2 < 256) ? wxd[row * 256 + k2] : Whhd[row * 256 + (k2 - 256)];
  }
  if (tid < 16) {
    int row = 256 * (tid >> 2) + 4 * jb + (tid & 3);
    scol0[tid] = Wihd[row * 257];
    sbias[tid] = bdp[row];
  }
  const float* hh_r = hh + (d & 1) * B_ * H_;
  float* hh_w = hh + ((d + 1) & 1) * B_ * H_;
  for (int bc2 = 0; bc2 < 2; ++bc2) {
    const int bc = half * 2 + bc2;
    __syncthreads();
    if (tid < 32) {
      int b = bc * 32 + tid;
      sden[tid] = 1.0f / ctxacc[((size_t)d * B_ + b) * 257 + 256];
      sinp[tid] = inp_buf[d * B_ + b];
    }
    __syncthreads();
    for (int idx = tid; idx < 32 * 512; idx += 512) {
      int b2 = idx >> 9, k2 = idx & 511;
      int b = bc * 32 + b2;
      sX[b2][k2] = (k2 < 256) ? ctxacc[((size_t)d * B_ + b) * 257 + k2] * sden[b2]
                              : hh_r[b * 256 + (k2 - 256)];
    }
    __syncthreads();
    {
      float a = sbias[rr] + scol0[rr] * sinp[bb];
      const float* wr = sW[rr];
      const float* xr = sX[bb];
      for (int k4 = 0; k4 < 512; k4 += 4)
        a += wr[k4] * xr[k4] + wr[k4 + 1] * xr[k4 + 1] + wr[k4 + 2] * xr[k4 + 2] + wr[k4 + 3] * xr[k4 + 3];
      sG[bb][rr] = a;
    }
    __syncthreads();
    if (rr < 4) {
      int b = bc * 32 + bb;
      int jh = 4 * jb + rr;
      float iv = sG[bb][rr], fv = sG[bb][4 + rr], gv = sG[bb][8 + rr], ov = sG[bb][12 + rr];
      float cn = sigf(fv) * cc[b * H_ + jh] + sigf(iv) * tanh_(gv);
      cc[b * H_ + jh] = cn;
      float hn = sigf(ov) * tanh_(cn);
      hh_w[b * H_ + jh] = hn;
      atomicAdd(&s_acc[(d + 1) * B_ + b], hn * Wa[jh]);
      atomicAdd(&pred_acc[d * B_ + b], hn * Wo[jh]);
    }
  }
}

__global__ void k_finish(const float* __restrict__ pred_acc, const float* __restrict__ bo,
                         float* __restrict__ dout) {
  int b = threadIdx.x;
  if (b < B_) dout[b * TRG_ + (TRG_ - 1)] = pred_acc[(TRG_ - 1) * B_ + b] + bo[0];
}

// ---------------- launch ----------------
extern "C" void kernel_launch(void* const* d_in, const int* in_sizes, int n_in,
                              void* d_out, int out_size, void* d_ws, size_t ws_size,
                              hipStream_t stream) {
  (void)in_sizes; (void)n_in; (void)out_size;
  float* dout = (float*)d_out;
  if (ws_size < WS_NEED) {
    k_wsfail<<<1, 1, 0, stream>>>(dout, (float)(ws_size >> 20));
    return;
  }
  const float* src1 = (const float*)d_in[0];
  const float* src2 = (const float*)d_in[1];
  const float* Wc   = (const float*)d_in[2];
  const float* bc   = (const float*)d_in[3];
  const float* Wihe = (const float*)d_in[4];
  const float* Whhe = (const float*)d_in[5];
  const float* bihe = (const float*)d_in[6];
  const float* bhhe = (const float*)d_in[7];
  const float* Wfc  = (const float*)d_in[8];
  const float* bfc  = (const float*)d_in[9];
  const float* Wf2  = (const float*)d_in[10];
  const float* bf2  = (const float*)d_in[11];
  const float* Wa   = (const float*)d_in[12];
  const float* Wihd = (const float*)d_in[13];
  const float* Whhd = (const float*)d_in[14];
  const float* bihd = (const float*)d_in[15];
  const float* bhhd = (const float*)d_in[16];
  const float* Wo   = (const float*)d_in[17];
  const float* bo   = (const float*)d_in[18];

  char* ws = (char*)d_ws;
  f16*   xf    = (f16*)(ws + XF_OFF);
  f16*   outs  = (f16*)(ws + OUTS_OFF);
  float* eproj = (float*)(ws + EPROJ_OFF);
  float* hh    = (float*)(ws + HH_OFF);
  float* cc    = (float*)(ws + CC_OFF);
  float* wxd   = (float*)(ws + WXD_OFF);
  float* vv    = (float*)(ws + VV_OFF);
  f16*   wfr   = (f16*)(ws + WFR_OFF);
  f16*   wll   = (f16*)(ws + WLL_OFF);
  f16*   wst   = (f16*)(ws + WST_OFF);
  float* zb    = (float*)(ws + ZERO_OFF);
  float* ctxacc   = zb;
  float* s_acc    = zb + CTX_CNT;
  float* pred_acc = s_acc + SAC_CNT;
  float* inp_buf  = pred_acc + PRD_CNT;

  k_zero<<<256, 256, 0, stream>>>(zb, ZERO_CNT);
  k_prep<<<8, 256, 0, stream>>>(Wfc, Wa, Wf2, bf2, bfc, bihd, bhhd, Wihd, vv);
  k_wxd<<<64, 256, 0, stream>>>(Wihd, Wfc, wxd);
  k_wprep3<<<144, 256, 0, stream>>>(Whhe, Wihe, bihe, bhhe, wfr, wll, wst);
  k_xf<<<B_ * 16, 128, 0, stream>>>(src1, src2, Wc, bc, xf);
  k_enc3<<<NBLK, 1024, 0, stream>>>(wfr, wll, wst, xf, outs, hh, cc);
  k_eproj<<<1024, 256, 0, stream>>>(outs, vv, eproj);
  k_decinit<<<1, 256, 0, stream>>>(outs, hh, Wa, vv, inp_buf, s_acc);
  for (int d = 0; d < TRG_; ++d) {
    k_attn<<<B_ * 16, 256, 0, stream>>>(d, eproj, outs, s_acc, ctxacc, pred_acc, inp_buf, dout, bo);
    k_cell<<<128, 512, 0, stream>>>(d, wxd, Whhd, Wihd, vv, ctxacc, inp_buf, hh, cc, s_acc, pred_acc, Wa, Wo);
  }
  k_finish<<<1, 128, 0, stream>>>(pred_acc, bo, dout);
}

// Round 10
// 12674.725 us; speedup vs baseline: 1.0822x; 1.0822x over previous
//
#include <hip/hip_runtime.h>
#include <hip/hip_fp16.h>

typedef __attribute__((ext_vector_type(4))) float f32x4;
typedef _Float16 f16;
typedef __attribute__((ext_vector_type(4))) _Float16 f16x4;
typedef __attribute__((ext_vector_type(8))) _Float16 f16x8;

#define DEV static __device__ __forceinline__

constexpr int B_ = 128, T_ = 2048, H_ = 256, TRG_ = 24;
constexpr int NBLK = 8;   // encoder blocks, 16 batches each

// ---------------- workspace layout (~150 MiB) ----------------
constexpr size_t XF_OFF   = 0;                                   // x A-fragments [t][blk][bb][32] f16
constexpr size_t XF_BYTES = (size_t)T_ * NBLK * 16 * 32 * 2;     // 16 MiB
constexpr size_t OUTS_OFF = XF_OFF + XF_BYTES;
constexpr size_t OUTS_BYTES = (size_t)B_ * T_ * H_ * 2;          // 128 MiB f16
constexpr size_t EPROJ_OFF = OUTS_OFF + OUTS_BYTES;
constexpr size_t EPROJ_BYTES = (size_t)B_ * T_ * 4;              // 1 MiB
constexpr size_t HH_OFF = EPROJ_OFF + EPROJ_BYTES;               // ping-pong decoder h (buf0 = enc final)
constexpr size_t HH_BYTES = 2ull * B_ * H_ * 4;
constexpr size_t CC_OFF = HH_OFF + HH_BYTES;
constexpr size_t CC_BYTES = (size_t)B_ * H_ * 4;
constexpr size_t WXD_OFF = CC_OFF + CC_BYTES;                    // Wih_d[:,1:] @ Wfc (1024x256) f32
constexpr size_t WXD_BYTES = 1024ull * 256 * 4;
constexpr size_t VV_OFF = WXD_OFF + WXD_BYTES;
constexpr size_t VV_BYTES = 8192;
constexpr size_t WALL_OFF = VV_OFF + VV_BYTES;                   // enc weights ks0-3 image (f16 frags)
constexpr size_t WALL_BYTES = 16384ull * 16;                     // 256 KiB
constexpr size_t W67_OFF = WALL_OFF + WALL_BYTES;                // streamed enc weights ks6,7 (x2 copies)
constexpr size_t W67_BYTES = 2ull * 8192 * 16;                   // 256 KiB
constexpr size_t XB_OFF = W67_OFF + W67_BYTES;                   // streamed x weights (x2 copies)
constexpr size_t XB_BYTES = 2ull * 4096 * 16;                    // 128 KiB
constexpr size_t ZERO_OFF = XB_OFF + XB_BYTES;
constexpr size_t CTX_CNT = 24ull * 128 * 257;   // ctxacc
constexpr size_t SAC_CNT = 25ull * 128;         // s_acc
constexpr size_t PRD_CNT = 24ull * 128;         // pred_acc
constexpr size_t INP_CNT = 25ull * 128;         // inp_buf
constexpr size_t ZERO_CNT = CTX_CNT + SAC_CNT + PRD_CNT + INP_CNT;
constexpr size_t WS_NEED = ZERO_OFF + ZERO_CNT * 4 + 1024;

// ---------------- helpers ----------------
DEV float sigf(float x)  { return 1.0f / (1.0f + __expf(-x)); }
DEV float tanh_(float x) { return 1.0f - 2.0f / (__expf(2.0f * x) + 1.0f); }

__global__ void k_wsfail(float* __restrict__ dout, float mb) { dout[0] = 1e6f + mb; }

__global__ void k_zero(float* __restrict__ p, size_t n) {
  size_t i = (size_t)blockIdx.x * blockDim.x + threadIdx.x;
  size_t s = (size_t)gridDim.x * blockDim.x;
  for (; i < n; i += s) p[i] = 0.f;
}

// ---------------- small precomputed vectors ----------------
__global__ void k_prep(const float* __restrict__ Wfc, const float* __restrict__ Wa,
                       const float* __restrict__ Wf2, const float* __restrict__ bf2_,
                       const float* __restrict__ bfc, const float* __restrict__ bihd,
                       const float* __restrict__ bhhd, const float* __restrict__ Wihd,
                       float* __restrict__ vv) {
  const int blk = blockIdx.x, tid = threadIdx.x;
  if (blk == 0) {
    float a = 0; for (int h = 0; h < 256; ++h) a += Wfc[h * 256 + tid] * Wa[256 + h];
    vv[tid] = a;
  } else if (blk == 1) {
    float a = 0; for (int h = 0; h < 256; ++h) a += Wfc[h * 256 + tid] * Wf2[h];
    vv[256 + tid] = a;
  } else if (blk == 2) {
    if (tid == 0) { float a = 0; for (int h = 0; h < 256; ++h) a += bfc[h] * Wa[256 + h]; vv[512] = a; }
    if (tid == 1) { float a = bf2_[0]; for (int h = 0; h < 256; ++h) a += bfc[h] * Wf2[h]; vv[513] = a; }
  } else if (blk < 7) {
    int j = (blk - 3) * 256 + tid;
    float a = bihd[j] + bhhd[j];
    for (int h = 0; h < 256; ++h) a += Wihd[j * 257 + 1 + h] * bfc[h];
    vv[576 + j] = a;
  }
}

// Wxd[j][k] = sum_h Wih_d[j][1+h] * Wfc[h][k]  (64 blocks x 16 rows)
__global__ void k_wxd(const float* __restrict__ Wihd, const float* __restrict__ Wfc,
                      float* __restrict__ wxd) {
  __shared__ float sR[16][256];
  const int tid = threadIdx.x;
  for (int i = tid; i < 16 * 256; i += 256) {
    int r = i >> 8, h = i & 255;
    sR[r][h] = Wihd[(blockIdx.x * 16 + r) * 257 + 1 + h];
  }
  __syncthreads();
  const int k = tid;
  float a[16];
#pragma unroll
  for (int r = 0; r < 16; ++r) a[r] = 0.f;
  for (int h = 0; h < 256; ++h) {
    float wv = Wfc[h * 256 + k];
#pragma unroll
    for (int r = 0; r < 16; ++r) a[r] += sR[r][h] * wv;
  }
#pragma unroll
  for (int r = 0; r < 16; ++r) wxd[(blockIdx.x * 16 + r) * 256 + k] = a[r];
}

// ---------------- encoder weight images (f16, MFMA B-fragment order) ----------------
__global__ void k_wprep(const float* __restrict__ Whh, const float* __restrict__ Wih,
                        const float* __restrict__ bih, const float* __restrict__ bhh,
                        f16* __restrict__ wall, f16* __restrict__ w67, f16* __restrict__ xb) {
  int i = blockIdx.x * 256 + threadIdx.x;
  if (i < 16384) {                 // wall ks0..3
    int l = i & 63, f = (i >> 6) & 63, ks = i >> 12;
    int q = f & 3, p = (f >> 2) & 1, w = f >> 3;
    int g = l >> 4, c16 = l & 15;
    int row = 256 * q + 16 * (w + 8 * p) + c16;
    f16x8 v;
#pragma unroll
    for (int jj = 0; jj < 8; ++jj) v[jj] = (f16)Whh[row * 256 + ks * 32 + 8 * g + jj];
    ((f16x8*)wall)[i] = v;
  } else if (i < 24576) {          // w67 ks6,7  (2 copies)
    int j = i - 16384;
    int l = j & 63, f = (j >> 6) & 63, ks = 6 + (j >> 12);
    int q = f & 3, p = (f >> 2) & 1, w = f >> 3;
    int g = l >> 4, c16 = l & 15;
    int row = 256 * q + 16 * (w + 8 * p) + c16;
    f16x8 v;
#pragma unroll
    for (int jj = 0; jj < 8; ++jj) v[jj] = (f16)Whh[row * 256 + ks * 32 + 8 * g + jj];
    ((f16x8*)w67)[j] = v;
    ((f16x8*)w67)[j + 8192] = v;
  } else if (i < 28672) {          // xb (2 copies)
    int j = i - 24576;
    int l = j & 63, f = (j >> 6) & 63;
    int q = f & 3, p = (f >> 2) & 1, w = f >> 3;
    int g = l >> 4, c16 = l & 15;
    int row = 256 * q + 16 * (w + 8 * p) + c16;
    f16x8 v;
#pragma unroll
    for (int jj = 0; jj < 8; ++jj) {
      int k = 8 * g + jj;
      float val = (k < 16) ? Wih[row * 16 + k] : (k == 16 ? (bih[row] + bhh[row]) : 0.f);
      v[jj] = (f16)val;
    }
    ((f16x8*)xb)[j] = v;
    ((f16x8*)xb)[j + 4096] = v;
  }
}

// ---------------- x A-fragment prepass (coalesced) ----------------
__global__ __launch_bounds__(128) void k_xf(const float* __restrict__ src1,
    const float* __restrict__ src2, const float* __restrict__ Wc, const float* __restrict__ bc,
    f16* __restrict__ xf) {
  const int b = blockIdx.x >> 4, tc = blockIdx.x & 15;
  const int t = tc * 128 + threadIdx.x;
  f16x8 v0, v1, v2, v3;
#pragma unroll
  for (int f = 0; f < 8; ++f)  v0[f] = (f16)src1[((size_t)b * T_ + t) * 15 + f];
#pragma unroll
  for (int f = 0; f < 7; ++f)  v1[f] = (f16)src1[((size_t)b * T_ + t) * 15 + 8 + f];
  float s = bc[0];
#pragma unroll
  for (int u = 0; u < 8; ++u) s += src2[((size_t)b * T_ + t) * 8 + u] * Wc[u];
  v1[7] = (f16)s;
  v2 = (f16x8){(f16)1.f, (f16)0.f, (f16)0.f, (f16)0.f, (f16)0.f, (f16)0.f, (f16)0.f, (f16)0.f};
  v3 = (f16x8){(f16)0.f, (f16)0.f, (f16)0.f, (f16)0.f, (f16)0.f, (f16)0.f, (f16)0.f, (f16)0.f};
  f16* o = xf + (((size_t)t * 8 + (b >> 4)) * 16 + (b & 15)) * 32;
  *(f16x8*)(o) = v0; *(f16x8*)(o + 8) = v1; *(f16x8*)(o + 16) = v2; *(f16x8*)(o + 24) = v3;
}

// ---------------- encoder: R8 structure + aligned single-b128 LDA (stride 264) ----------
__global__ __launch_bounds__(512, 2) void k_enc(const float* __restrict__ Whh,
    const f16* __restrict__ wall, const f16* __restrict__ w67, const f16* __restrict__ xb,
    const f16* __restrict__ xf, f16* __restrict__ outs,
    float* __restrict__ hh0, float* __restrict__ cc0) {
  const int blk = blockIdx.x, tid = threadIdx.x;
  const int w = tid >> 6, l = tid & 63, g = l >> 4, c16 = l & 15;
  __shared__ f16x8 Wl[8192];                      // ks4,5: [((ksl*8+w)*2+p)*4+q][lane] = 128 KiB
  __shared__ __align__(16) f16 hbuf[2][16 * 264]; // ping-pong h[b][jh], stride 264 (16B-aligned rows)

  // LDS-resident weights ks4,5 (setup-only f32 read)
#pragma unroll
  for (int ksl = 0; ksl < 2; ++ksl)
#pragma unroll
    for (int p = 0; p < 2; ++p)
#pragma unroll
      for (int q = 0; q < 4; ++q) {
        const int row = 256 * q + 16 * (w + 8 * p) + c16;
        const float* s = Whh + row * 256 + (4 + ksl) * 32 + 8 * g;
        f16x8 v;
#pragma unroll
        for (int jj = 0; jj < 8; ++jj) v[jj] = (f16)s[jj];
        Wl[((((ksl * 8 + w) * 2 + p) * 4 + q)) * 64 + l] = v;
      }
  // ks0..3 weights from f16 fragment image
  const f16x8* wallv = (const f16x8*)wall;
  f16x8 wf[4][2][4];
#pragma unroll
  for (int ks = 0; ks < 4; ++ks)
#pragma unroll
    for (int p = 0; p < 2; ++p)
#pragma unroll
      for (int q = 0; q < 4; ++q)
        wf[ks][p][q] = wallv[(size_t)(ks * 64 + w * 8 + p * 4 + q) * 64 + l];
  for (int i = tid; i < 16 * 264; i += 512) hbuf[0][i] = (f16)0.f;
  __syncthreads();

  f32x4 cst[2];
  cst[0] = (f32x4){0.f, 0.f, 0.f, 0.f};
  cst[1] = (f32x4){0.f, 0.f, 0.f, 0.f};

  const f16x8* w67v = (const f16x8*)w67;
  const f16x8* xbv = (const f16x8*)xb;
  const int fb = w * 8;
  const int obl = tid >> 5, ou = tid & 31;        // outs-writer mapping

#define LDA(ks) (*(const f16x8*)(hb + c16 * 264 + (ks) * 32 + 8 * g))
#define MF8(A, BB) \
  { _Pragma("unroll") for (int p = 0; p < 2; ++p) \
    _Pragma("unroll") for (int q = 0; q < 4; ++q) \
      acc[p][q] = __builtin_amdgcn_mfma_f32_16x16x32_f16((A), BB[p][q], acc[p][q], 0, 0, 0); }
#define STAGE(SRC) \
  { _Pragma("unroll") for (int p = 0; p < 2; ++p) \
    _Pragma("unroll") for (int q = 0; q < 4; ++q) \
      st[p][q] = (SRC)[(size_t)(fb + p * 4 + q) * 64 + l]; }

  f16x8 xac = *(const f16x8*)(xf + ((size_t)blk * 16 + c16) * 32 + 8 * g);   // t=0

  for (int t = 0; t < T_; ++t) {
    const int cp = t & 1;
    const f16* hb = hbuf[cp];
    const f16x8* sx = xbv + (size_t)cp * 4096;
    const f16x8* s6 = w67v + (size_t)cp * 8192;
    const f16x8* s7 = s6 + 4096;

    f16x8 st[2][4];
    STAGE(sx);
    // prefetch next x A-frag
    const int tn = (t + 1 < T_) ? (t + 1) : t;
    const f16x8 xan = *(const f16x8*)(xf + (((size_t)tn * 8 + blk) * 16 + c16) * 32 + 8 * g);

    // coalesced outs write of h(t-1) from hbuf[cp] (16B/thread), drains under MFMAs
    if (t > 0) {
      const f16x8 hv = *(const f16x8*)(hb + obl * 264 + ou * 8);
      *(f16x8*)(outs + ((size_t)(blk * 16 + obl) * T_ + (t - 1)) * H_ + ou * 8) = hv;
    }

    f32x4 acc[2][4];
#pragma unroll
    for (int p = 0; p < 2; ++p)
#pragma unroll
      for (int q = 0; q < 4; ++q) acc[p][q] = (f32x4){0.f, 0.f, 0.f, 0.f};

    // ks0-2 from wf (covers x-stage latency)
    { const f16x8 a = LDA(0); MF8(a, wf[0]); }
    { const f16x8 a = LDA(1); MF8(a, wf[1]); }
    { const f16x8 a = LDA(2); MF8(a, wf[2]); }
    // x-part; restage <- ks6
    MF8(xac, st);
    STAGE(s6);
    // ks3 (wf) + ks4 (LDS) cover ks6 latency
    { const f16x8 a = LDA(3); MF8(a, wf[3]); }
    { const f16x8 a = LDA(4);
#pragma unroll
      for (int p = 0; p < 2; ++p)
#pragma unroll
        for (int q = 0; q < 4; ++q) {
          const f16x8 bb = Wl[(((0 * 8 + w) * 2 + p) * 4 + q) * 64 + l];
          acc[p][q] = __builtin_amdgcn_mfma_f32_16x16x32_f16(a, bb, acc[p][q], 0, 0, 0);
        } }
    // ks6; restage <- ks7
    { const f16x8 a = LDA(6); MF8(a, st); }
    STAGE(s7);
    // ks5 (LDS) covers ks7 latency
    { const f16x8 a = LDA(5);
#pragma unroll
      for (int p = 0; p < 2; ++p)
#pragma unroll
        for (int q = 0; q < 4; ++q) {
          const f16x8 bb = Wl[(((1 * 8 + w) * 2 + p) * 4 + q) * 64 + l];
          acc[p][q] = __builtin_amdgcn_mfma_f32_16x16x32_f16(a, bb, acc[p][q], 0, 0, 0);
        } }
    // ks7
    { const f16x8 a = LDA(7); MF8(a, st); }

    // epilogue: LSTM cell, write h into ping-pong buffer
    f16* hw = hbuf[cp ^ 1];
#pragma unroll
    for (int p = 0; p < 2; ++p) {
      const int jh = 16 * (w + 8 * p) + c16;
#pragma unroll
      for (int r = 0; r < 4; ++r) {
        const float iv = acc[p][0][r], fv = acc[p][1][r], gv = acc[p][2][r], ov = acc[p][3][r];
        const float cn = sigf(fv) * cst[p][r] + sigf(iv) * tanh_(gv);
        cst[p][r] = cn;
        const float hn = sigf(ov) * tanh_(cn);
        const int bl = 4 * g + r;
        hw[bl * 264 + jh] = (f16)hn;
        if (t == T_ - 1) {
          hh0[(blk * 16 + bl) * H_ + jh] = hn;
          cc0[(blk * 16 + bl) * H_ + jh] = cn;
        }
      }
    }
    xac = xan;
    __syncthreads();
  }
  // final outs row: h(T-1) lives in hbuf[0] (T even)
  {
    const f16x8 hv = *(const f16x8*)(hbuf[0] + obl * 264 + ou * 8);
    *(f16x8*)(outs + ((size_t)(blk * 16 + obl) * T_ + (T_ - 1)) * H_ + ou * 8) = hv;
  }
#undef LDA
#undef MF8
#undef STAGE
}

// ---------------- eproj = outs.v + c0 ----------------
__global__ __launch_bounds__(256) void k_eproj(const f16* __restrict__ outs,
    const float* __restrict__ vv, float* __restrict__ eproj) {
  const int l = threadIdx.x & 63, wv = threadIdx.x >> 6;
  const float v0 = vv[4 * l], v1 = vv[4 * l + 1], v2 = vv[4 * l + 2], v3 = vv[4 * l + 3];
  const float c0 = vv[512];
  const int base = blockIdx.x * 256;
  for (int it = 0; it < 64; ++it) {
    const int row = base + it * 4 + wv;
    const f16x4 o = *(const f16x4*)(outs + (size_t)row * H_ + l * 4);
    float s = (float)o[0] * v0 + (float)o[1] * v1 + (float)o[2] * v2 + (float)o[3] * v3;
#pragma unroll
    for (int off = 32; off > 0; off >>= 1) s += __shfl_down(s, off);
    if (l == 0) eproj[row] = s + c0;
  }
}

// ---------------- decoder init: token + s0 ----------------
__global__ void k_decinit(const f16* __restrict__ outs, const float* __restrict__ hh,
                          const float* __restrict__ Wa, const float* __restrict__ vv,
                          float* __restrict__ inp_buf, float* __restrict__ s_acc) {
  int b = threadIdx.x;
  if (b >= B_) return;
  float tok = vv[513];
  const f16* op = outs + ((size_t)b * T_ + (T_ - 1)) * H_;
  for (int k = 0; k < H_; ++k) tok += (float)op[k] * vv[256 + k];
  float s0 = 0;
  for (int j = 0; j < H_; ++j) s0 += hh[b * H_ + j] * Wa[j];
  inp_buf[b] = tok;
  s_acc[b] = s0;
}

// ---------------- attention: ctx' = softmax(tanh(s+eproj)) @ outs ----------------
__global__ void k_attn(int d, const float* __restrict__ eproj, const f16* __restrict__ outs,
                       const float* __restrict__ s_acc, float* __restrict__ ctxacc,
                       const float* __restrict__ pred_acc, float* __restrict__ inp_buf,
                       float* __restrict__ dout, const float* __restrict__ bo) {
  const int b = blockIdx.x >> 4, ch = blockIdx.x & 15;
  const int k = threadIdx.x;
  if (d > 0 && ch == 0 && k == 0) {
    float pv = pred_acc[(d - 1) * B_ + b] + bo[0];
    inp_buf[d * B_ + b] = pv;
    dout[b * TRG_ + (d - 1)] = pv;
  }
  __shared__ float swt[128];
  const float s = s_acc[d * B_ + b];
  if (k < 128) {
    float e = eproj[b * T_ + ch * 128 + k];
    swt[k] = __expf(tanh_(s + e));
  }
  __syncthreads();
  float acc = 0.f;
  const f16* op = outs + ((size_t)b * T_ + ch * 128) * H_ + k;
#pragma unroll 8
  for (int tt = 0; tt < 128; ++tt) acc += swt[tt] * (float)op[tt * H_];
  atomicAdd(&ctxacc[((size_t)d * B_ + b) * 257 + k], acc);
  if (k == 0) {
    float sw = 0;
    for (int tt = 0; tt < 128; ++tt) sw += swt[tt];
    atomicAdd(&ctxacc[((size_t)d * B_ + b) * 257 + 256], sw);
  }
}

// ---------------- decoder LSTM cell (128 blocks: 64 jb x 2 batch-halves, b128 dot) ----------
__global__ __launch_bounds__(512) void k_cell(int d, const float* __restrict__ wxd,
    const float* __restrict__ Whhd, const float* __restrict__ Wihd, const float* __restrict__ vv,
    const float* __restrict__ ctxacc, const float* __restrict__ inp_buf,
    float* __restrict__ hh, float* __restrict__ cc,
    float* __restrict__ s_acc, float* __restrict__ pred_acc,
    const float* __restrict__ Wa, const float* __restrict__ Wo) {
  const int jb = blockIdx.x & 63, half = blockIdx.x >> 6;
  const int tid = threadIdx.x;
  const int rr = tid & 15, bb = tid >> 4;
  __shared__ __align__(16) float sW[16][516];
  __shared__ __align__(16) float sX[32][516];
  __shared__ float sG[32][17];
  __shared__ float sden[32], sinp[32];
  __shared__ float scol0[16], sbias[16];
  const float* bdp = vv + 576;
  for (int idx = tid; idx < 16 * 512; idx += 512) {
    int r2 = idx >> 9, k2 = idx & 511;
    int row = 256 * (r2 >> 2) + 4 * jb + (r2 & 3);
    sW[r2][k2] = (k2 < 256) ? wxd[row * 256 + k2] : Whhd[row * 256 + (k2 - 256)];
  }
  if (tid < 16) {
    int row = 256 * (tid >> 2) + 4 * jb + (tid & 3);
    scol0[tid] = Wihd[row * 257];
    sbias[tid] = bdp[row];
  }
  const float* hh_r = hh + (d & 1) * B_ * H_;
  float* hh_w = hh + ((d + 1) & 1) * B_ * H_;
  for (int bc2 = 0; bc2 < 2; ++bc2) {
    const int bc = half * 2 + bc2;
    __syncthreads();
    if (tid < 32) {
      int b = bc * 32 + tid;
      sden[tid] = 1.0f / ctxacc[((size_t)d * B_ + b) * 257 + 256];
      sinp[tid] = inp_buf[d * B_ + b];
    }
    __syncthreads();
    for (int idx = tid; idx < 32 * 512; idx += 512) {
      int b2 = idx >> 9, k2 = idx & 511;
      int b = bc * 32 + b2;
      sX[b2][k2] = (k2 < 256) ? ctxacc[((size_t)d * B_ + b) * 257 + k2] * sden[b2]
                              : hh_r[b * 256 + (k2 - 256)];
    }
    __syncthreads();
    {
      float a = sbias[rr] + scol0[rr] * sinp[bb];
      const float4* wr4 = (const float4*)sW[rr];
      const float4* xr4 = (const float4*)sX[bb];
      for (int k4 = 0; k4 < 128; ++k4) {
        const float4 wv = wr4[k4], xv = xr4[k4];
        a += wv.x * xv.x + wv.y * xv.y + wv.z * xv.z + wv.w * xv.w;
      }
      sG[bb][rr] = a;
    }
    __syncthreads();
    if (rr < 4) {
      int b = bc * 32 + bb;
      int jh = 4 * jb + rr;
      float iv = sG[bb][rr], fv = sG[bb][4 + rr], gv = sG[bb][8 + rr], ov = sG[bb][12 + rr];
      float cn = sigf(fv) * cc[b * H_ + jh] + sigf(iv) * tanh_(gv);
      cc[b * H_ + jh] = cn;
      float hn = sigf(ov) * tanh_(cn);
      hh_w[b * H_ + jh] = hn;
      atomicAdd(&s_acc[(d + 1) * B_ + b], hn * Wa[jh]);
      atomicAdd(&pred_acc[d * B_ + b], hn * Wo[jh]);
    }
  }
}

__global__ void k_finish(const float* __restrict__ pred_acc, const float* __restrict__ bo,
                         float* __restrict__ dout) {
  int b = threadIdx.x;
  if (b < B_) dout[b * TRG_ + (TRG_ - 1)] = pred_acc[(TRG_ - 1) * B_ + b] + bo[0];
}

// ---------------- launch ----------------
extern "C" void kernel_launch(void* const* d_in, const int* in_sizes, int n_in,
                              void* d_out, int out_size, void* d_ws, size_t ws_size,
                              hipStream_t stream) {
  (void)in_sizes; (void)n_in; (void)out_size;
  float* dout = (float*)d_out;
  if (ws_size < WS_NEED) {
    k_wsfail<<<1, 1, 0, stream>>>(dout, (float)(ws_size >> 20));
    return;
  }
  const float* src1 = (const float*)d_in[0];
  const float* src2 = (const float*)d_in[1];
  const float* Wc   = (const float*)d_in[2];
  const float* bc   = (const float*)d_in[3];
  const float* Wihe = (const float*)d_in[4];
  const float* Whhe = (const float*)d_in[5];
  const float* bihe = (const float*)d_in[6];
  const float* bhhe = (const float*)d_in[7];
  const float* Wfc  = (const float*)d_in[8];
  const float* bfc  = (const float*)d_in[9];
  const float* Wf2  = (const float*)d_in[10];
  const float* bf2  = (const float*)d_in[11];
  const float* Wa   = (const float*)d_in[12];
  const float* Wihd = (const float*)d_in[13];
  const float* Whhd = (const float*)d_in[14];
  const float* bihd = (const float*)d_in[15];
  const float* bhhd = (const float*)d_in[16];
  const float* Wo   = (const float*)d_in[17];
  const float* bo   = (const float*)d_in[18];

  char* ws = (char*)d_ws;
  f16*   xf    = (f16*)(ws + XF_OFF);
  f16*   outs  = (f16*)(ws + OUTS_OFF);
  float* eproj = (float*)(ws + EPROJ_OFF);
  float* hh    = (float*)(ws + HH_OFF);
  float* cc    = (float*)(ws + CC_OFF);
  float* wxd   = (float*)(ws + WXD_OFF);
  float* vv    = (float*)(ws + VV_OFF);
  f16*   wall  = (f16*)(ws + WALL_OFF);
  f16*   w67   = (f16*)(ws + W67_OFF);
  f16*   xb    = (f16*)(ws + XB_OFF);
  float* zb    = (float*)(ws + ZERO_OFF);
  float* ctxacc   = zb;
  float* s_acc    = zb + CTX_CNT;
  float* pred_acc = s_acc + SAC_CNT;
  float* inp_buf  = pred_acc + PRD_CNT;

  k_zero<<<256, 256, 0, stream>>>(zb, ZERO_CNT);
  k_prep<<<8, 256, 0, stream>>>(Wfc, Wa, Wf2, bf2, bfc, bihd, bhhd, Wihd, vv);
  k_wxd<<<64, 256, 0, stream>>>(Wihd, Wfc, wxd);
  k_wprep<<<112, 256, 0, stream>>>(Whhe, Wihe, bihe, bhhe, wall, w67, xb);
  k_xf<<<B_ * 16, 128, 0, stream>>>(src1, src2, Wc, bc, xf);
  k_enc<<<NBLK, 512, 0, stream>>>(Whhe, wall, w67, xb, xf, outs, hh, cc);
  k_eproj<<<1024, 256, 0, stream>>>(outs, vv, eproj);
  k_decinit<<<1, 256, 0, stream>>>(outs, hh, Wa, vv, inp_buf, s_acc);
  for (int d = 0; d < TRG_; ++d) {
    k_attn<<<B_ * 16, 256, 0, stream>>>(d, eproj, outs, s_acc, ctxacc, pred_acc, inp_buf, dout, bo);
    k_cell<<<128, 512, 0, stream>>>(d, wxd, Whhd, Wihd, vv, ctxacc, inp_buf, hh, cc, s_acc, pred_acc, Wa, Wo);
  }
  k_finish<<<1, 128, 0, stream>>>(pred_acc, bo, dout);
}